// Round 5
// baseline (1155.465 us; speedup 1.0000x reference)
//
#include <hip/hip_runtime.h>
#include <stdint.h>
#include <math.h>

#define NB      8
#define NPTS    16384
#define NPOINT  512
#define NCH     128
#define KNBR    32
#define R2      0.04f

#define FPS_THR 512                  // 8 waves
#define PPT     32                   // points per thread
#define NPAIR   16                   // v2f pairs per thread

// ws layout
#define CENT_OFF 0                   // 8*512*4 = 16384 B
#define FT_OFF   16384               // transposed features

typedef float v2f __attribute__((ext_vector_type(2)));

// Two points' squared distances to the centroid in ONE asm block.
// Exact: per-element rn sub/mul/add, association ((x2+y2)+z2) == reference.
// neg modifiers give exact subtraction (a + (-b) == a - b in IEEE).
__device__ __forceinline__ v2f pair_dist(v2f x, v2f y, v2f z,
                                         v2f cx, v2f cy, v2f cz) {
    v2f dx, dy, dz;
    asm("v_pk_add_f32 %0, %3, %6 neg_lo:[0,1] neg_hi:[0,1]\n\t"
        "v_pk_add_f32 %1, %4, %7 neg_lo:[0,1] neg_hi:[0,1]\n\t"
        "v_pk_add_f32 %2, %5, %8 neg_lo:[0,1] neg_hi:[0,1]\n\t"
        "v_pk_mul_f32 %0, %0, %0\n\t"
        "v_pk_mul_f32 %1, %1, %1\n\t"
        "v_pk_mul_f32 %2, %2, %2\n\t"
        "v_pk_add_f32 %0, %0, %1\n\t"
        "v_pk_add_f32 %0, %0, %2"
        : "=&v"(dx), "=&v"(dy), "=&v"(dz)
        : "v"(x), "v"(y), "v"(z), "v"(cx), "v"(cy), "v"(cz));
    return dx;
}

// argmax step over (value desc, index asc) using DPP permute (VALU latency)
#define DPP_ARG_STEP(v, p, CTRL) do {                                          \
    float _ov = __builtin_bit_cast(float, __builtin_amdgcn_update_dpp(         \
        __builtin_bit_cast(int, (v)), __builtin_bit_cast(int, (v)),            \
        (CTRL), 0xF, 0xF, false));                                             \
    int _op = __builtin_amdgcn_update_dpp((p), (p), (CTRL), 0xF, 0xF, false);  \
    bool _t = (_ov > (v)) || ((_ov == (v)) && (_op < (p)));                    \
    (v) = _t ? _ov : (v);                                                      \
    (p) = _t ? _op : (p);                                                      \
} while (0)

#define SHFL_ARG_STEP(v, p, XORAMT) do {                                       \
    float _ov = __shfl_xor((v), (XORAMT), 64);                                 \
    int   _op = __shfl_xor((p), (XORAMT), 64);                                 \
    bool _t = (_ov > (v)) || ((_ov == (v)) && (_op < (p)));                    \
    (v) = _t ? _ov : (v);                                                      \
    (p) = _t ? _op : (p);                                                      \
} while (0)

// -------- kernel 1: FPS (blocks 0..7, one CU per batch) + transpose ---------
// 8 waves * 32 pts/thread, pts stored as 16 v2f pairs (elem0 = k*512+tid,
// elem1 = (k+16)*512+tid). Distance core = 8 packed ops/pair via inline asm.
// One barrier/iter, parity-buffered LDS partials, uniform coords reload.
__global__
__attribute__((amdgpu_flat_work_group_size(FPS_THR, FPS_THR)))
__attribute__((amdgpu_waves_per_eu(2, 2)))
void fps_transpose_kernel(const float* __restrict__ xyz,
                          const float* __restrict__ feat,
                          float* __restrict__ out,     // new_xyz at [0,12288)
                          int* __restrict__ cent,      // ws: 8*512 ints
                          float* __restrict__ ft,      // ws: (B,N,128) fp32
                          int use_ft)
{
    const int blk = blockIdx.x;
    const int tid = threadIdx.x;

    if (blk < NB) {
        const int b = blk;
        const float* xb = xyz + (size_t)b * NPTS * 3;
        v2f px[NPAIR], py[NPAIR], pz[NPAIR];
        float d[PPT];
#pragma unroll
        for (int j = 0; j < NPAIR; ++j) {
            int p0 = j * FPS_THR + tid;
            int p1 = (j + 16) * FPS_THR + tid;
            px[j] = (v2f){xb[p0 * 3 + 0], xb[p1 * 3 + 0]};
            py[j] = (v2f){xb[p0 * 3 + 1], xb[p1 * 3 + 1]};
            pz[j] = (v2f){xb[p0 * 3 + 2], xb[p1 * 3 + 2]};
            d[j] = 1e10f;
            d[j + 16] = 1e10f;
        }
        // parity-double-buffered partial slots (32 = 8 waves * 4 rows)
        __shared__ float s_v[2][32];
        __shared__ int   s_p[2][32];
        const int lane = tid & 63;
        const int wid  = tid >> 6;

        float cx = xb[0], cy = xb[1], cz = xb[2];
        if (tid == 0) {
            cent[b * NPOINT + 0] = 0;
            out[((size_t)b * NPOINT + 0) * 3 + 0] = cx;
            out[((size_t)b * NPOINT + 0) * 3 + 1] = cy;
            out[((size_t)b * NPOINT + 0) * 3 + 2] = cz;
        }

        for (int i = 1; i < NPOINT; ++i) {
            const v2f cxv = (v2f){cx, cx};
            const v2f cyv = (v2f){cy, cy};
            const v2f czv = (v2f){cz, cz};
            // phase 1: packed min-distance update, value-only tracking.
            // 4 independent max accumulators break the dependence chain;
            // fmaxf(fmaxf) nesting fuses to v_max3_f32.
            float vm0 = -1.0f, vm1 = -1.0f, vm2 = -1.0f, vm3 = -1.0f;
#pragma unroll
            for (int j = 0; j < NPAIR; ++j) {
                v2f s = pair_dist(px[j], py[j], pz[j], cxv, cyv, czv);
                float nd0 = fminf(d[j],      s.x);   // np.minimum, exact
                float nd1 = fminf(d[j + 16], s.y);
                d[j]      = nd0;
                d[j + 16] = nd1;
                float nm = fmaxf(nd0, nd1);
                if ((j & 3) == 0)      vm0 = fmaxf(vm0, nm);
                else if ((j & 3) == 1) vm1 = fmaxf(vm1, nm);
                else if ((j & 3) == 2) vm2 = fmaxf(vm2, nm);
                else                   vm3 = fmaxf(vm3, nm);
            }
            float vmax = fmaxf(fmaxf(vm0, vm1), fmaxf(vm2, vm3));
            // phase 2: recover earliest k with d[k]==vmax (fmax returns an
            // operand so a match exists; descending scan -> smallest k wins;
            // k ascending == global index ascending -> reference tie-break)
            int bk = PPT - 1;
#pragma unroll
            for (int k = PPT - 2; k >= 0; --k) bk = (d[k] == vmax) ? k : bk;

            float rv = vmax;
            int   rp = bk * FPS_THR + tid;   // global point index
            // 16-lane row argmax (val desc, idx asc): 4 DPP steps
            DPP_ARG_STEP(rv, rp, 0xB1);   // xor 1
            DPP_ARG_STEP(rv, rp, 0x4E);   // xor 2
            DPP_ARG_STEP(rv, rp, 0x141);  // row_half_mirror
            DPP_ARG_STEP(rv, rp, 0x140);  // row_mirror
            const int par = i & 1;
            if ((lane & 15) == 0) {       // 4 row leaders per wave
                int slot = wid * 4 + (lane >> 4);
                s_v[par][slot] = rv;
                s_p[par][slot] = rp;
            }
            __syncthreads();              // the ONLY barrier per iteration
            // all waves redundantly reduce 32 partials
            float fv = s_v[par][lane & 31];
            int   fp = s_p[par][lane & 31];
            DPP_ARG_STEP(fv, fp, 0xB1);
            DPP_ARG_STEP(fv, fp, 0x4E);
            DPP_ARG_STEP(fv, fp, 0x141);
            DPP_ARG_STEP(fv, fp, 0x140);
            SHFL_ARG_STEP(fv, fp, 16);
            const int cur = __builtin_amdgcn_readfirstlane(fp);
            // uniform coords reload from global (L1/L2-resident, 192 KB/batch)
            cx = xb[cur * 3 + 0];
            cy = xb[cur * 3 + 1];
            cz = xb[cur * 3 + 2];
            if (tid == 0) {
                cent[b * NPOINT + i] = cur;
                size_t o = ((size_t)b * NPOINT + i) * 3;
                out[o + 0] = cx; out[o + 1] = cy; out[o + 2] = cz;
            }
        }
    } else {
        if (!use_ft) return;
        // transpose feat (B,128,N) -> ft (B,N,128); 32x32 tile, 512 threads
        int t  = blk - NB;
        int b  = t >> 11;          // 2048 tiles per batch
        int r  = t & 2047;
        int ct = r >> 9;           // channel tile (4)
        int nt = r & 511;          // point tile (512)
        __shared__ float tile[32][33];
        int tx = tid & 31, ty = tid >> 5;   // ty 0..15
        tile[ty][tx] =
            feat[((size_t)b * NCH + ct * 32 + ty) * NPTS + nt * 32 + tx];
        tile[ty + 16][tx] =
            feat[((size_t)b * NCH + ct * 32 + ty + 16) * NPTS + nt * 32 + tx];
        __syncthreads();
        ft[((size_t)b * NPTS + nt * 32 + ty) * NCH + ct * 32 + tx] =
            tile[tx][ty];
        ft[((size_t)b * NPTS + nt * 32 + ty + 16) * NCH + ct * 32 + tx] =
            tile[tx][ty + 16];
    }
}

// -------- kernel 2: ball query + grouped max pool ---------------------------
__global__ __launch_bounds__(256, 4)
void query_pool_kernel(const float* __restrict__ xyz,
                       const float* __restrict__ feat,
                       const float* __restrict__ ft,
                       const int* __restrict__ cent,
                       float* __restrict__ out_sub,   // (B,128,512)
                       int use_ft)
{
    const int tid  = threadIdx.x;
    const int widx = tid >> 6;
    const int lane = tid & 63;
    const int w = blockIdx.x * 4 + widx;   // 0..4095
    const int b = w >> 9;
    const int s = w & 511;

    const float* xb = xyz + (size_t)b * NPTS * 3;
    const int ci = cent[b * NPOINT + s];
    const float sx = xb[ci * 3 + 0];
    const float sy = xb[ci * 3 + 1];
    const float sz = xb[ci * 3 + 2];
    const float snorm = __fadd_rn(__fadd_rn(__fmul_rn(sx, sx),
                                            __fmul_rn(sy, sy)),
                                  __fmul_rn(sz, sz));

    __shared__ int lidx[4][KNBR];
    int found = 0;
    for (int base = 0; base < NPTS && found < KNBR; base += 64) {
        int j = base + lane;
        float dx = xb[j * 3 + 0];
        float dy = xb[j * 3 + 1];
        float dz = xb[j * 3 + 2];
        float dn = __fadd_rn(__fadd_rn(__fmul_rn(dx, dx),
                                       __fmul_rn(dy, dy)),
                             __fmul_rn(dz, dz));
        float dot = __fadd_rn(__fadd_rn(__fmul_rn(sx, dx),
                                        __fmul_rn(sy, dy)),
                              __fmul_rn(sz, dz));
        // reference order: d = -2*dot; d += snorm; d += dnorm
        float d = __fadd_rn(__fadd_rn(__fmul_rn(-2.0f, dot), snorm), dn);
        bool inball = !(d > R2);
        unsigned long long mask = __ballot(inball);
        int before = (int)__popcll(mask & ((1ULL << lane) - 1ULL));
        int slot = found + before;
        if (inball && slot < KNBR) lidx[widx][slot] = j;
        found += (int)__popcll(mask);
    }
    int cnt = found < KNBR ? found : KNBR;   // cnt >= 1 (self in ball)
    __syncthreads();

    float a0 = -INFINITY, a1 = -INFINITY;
    if (use_ft) {
        for (int m = 0; m < cnt; ++m) {
            int i = lidx[widx][m];
            const float* row = ft + ((size_t)b * NPTS + i) * NCH;
            a0 = fmaxf(a0, row[lane]);
            a1 = fmaxf(a1, row[lane + 64]);
        }
    } else {
        for (int m = 0; m < cnt; ++m) {
            int i = lidx[widx][m];
            a0 = fmaxf(a0, feat[((size_t)b * NCH + lane) * NPTS + i]);
            a1 = fmaxf(a1, feat[((size_t)b * NCH + lane + 64) * NPTS + i]);
        }
    }
    out_sub[((size_t)b * NCH + lane) * NPOINT + s] = a0;
    out_sub[((size_t)b * NCH + lane + 64) * NPOINT + s] = a1;
}

extern "C" void kernel_launch(void* const* d_in, const int* in_sizes, int n_in,
                              void* d_out, int out_size, void* d_ws, size_t ws_size,
                              hipStream_t stream)
{
    const float* xyz  = (const float*)d_in[0];   // (8,16384,3)
    const float* feat = (const float*)d_in[1];   // (8,128,16384)
    float* out = (float*)d_out;                  // [new_xyz | sub_features]

    int*   cent = (int*)((char*)d_ws + CENT_OFF);
    float* ft   = (float*)((char*)d_ws + FT_OFF);
    const size_t need_ft = FT_OFF + (size_t)NB * NPTS * NCH * 4ull;
    int use_ft = (ws_size >= need_ft) ? 1 : 0;

    int nblocks1 = NB + (use_ft ? NB * (NCH / 32) * (NPTS / 32) : 0);
    hipLaunchKernelGGL(fps_transpose_kernel, dim3(nblocks1), dim3(FPS_THR), 0, stream,
                       xyz, feat, out, cent, ft, use_ft);

    hipLaunchKernelGGL(query_pool_kernel, dim3((NB * NPOINT) / 4), dim3(256), 0, stream,
                       xyz, feat, ft, cent, out + (size_t)NB * NPOINT * 3, use_ft);
}

// Round 6
// 1081.439 us; speedup vs baseline: 1.0685x; 1.0685x over previous
//
#include <hip/hip_runtime.h>
#include <stdint.h>
#include <math.h>

#define NB      8
#define NPTS    16384
#define NPOINT  512
#define NCH     128
#define KNBR    32
#define R2      0.04f

#define FPS_THR 512                  // 8 waves
#define PPT     32                   // points (= chunks) per thread

// ws layout
#define CENT_OFF 0                   // 8*512*4 = 16 KB
#define MAP_OFF  16384               // 8*16384*4 = 512 KB sorted->orig map
#define FT_OFF   (16384 + 524288)    // transposed features

// argmax step over (value desc, index asc) using DPP permute (VALU latency)
#define DPP_ARG_STEP(v, p, CTRL) do {                                          \
    float _ov = __builtin_bit_cast(float, __builtin_amdgcn_update_dpp(         \
        __builtin_bit_cast(int, (v)), __builtin_bit_cast(int, (v)),            \
        (CTRL), 0xF, 0xF, false));                                             \
    int _op = __builtin_amdgcn_update_dpp((p), (p), (CTRL), 0xF, 0xF, false);  \
    bool _t = (_ov > (v)) || ((_ov == (v)) && (_op < (p)));                    \
    (v) = _t ? _ov : (v);                                                      \
    (p) = _t ? _op : (p);                                                      \
} while (0)

#define SHFL_ARG_STEP(v, p, XORAMT) do {                                       \
    float _ov = __shfl_xor((v), (XORAMT), 64);                                 \
    int   _op = __shfl_xor((p), (XORAMT), 64);                                 \
    bool _t = (_ov > (v)) || ((_ov == (v)) && (_op < (p)));                    \
    (v) = _t ? _ov : (v);                                                      \
    (p) = _t ? _op : (p);                                                      \
} while (0)

// 8x8x8 morton cell id (9 bits) for a point in [0,1)^3
__device__ __forceinline__ int cell_of(float x, float y, float z) {
    int cx = (int)(x * 8.0f); cx = cx < 0 ? 0 : (cx > 7 ? 7 : cx);
    int cy = (int)(y * 8.0f); cy = cy < 0 ? 0 : (cy > 7 ? 7 : cy);
    int cz = (int)(z * 8.0f); cz = cz < 0 ? 0 : (cz > 7 ? 7 : cz);
    int m = 0;
    m |= ((cx & 1) << 2) | ((cx & 2) << 4) | ((cx & 4) << 6);
    m |= ((cy & 1) << 1) | ((cy & 2) << 3) | ((cy & 4) << 5);
    m |=  (cz & 1)       | ((cz & 2) << 2) | ((cz & 4) << 4);
    return m;
}

// -------- kernel 1: FPS with exact chunk skipping (blocks 0..7) + transpose -
// Setup: morton counting-sort (LDS histogram + scan) -> gmap (sorted->orig),
// gather sorted coords + orig indices into registers; per-chunk (64 sorted
// points across the wave's 64 lanes at register slot k) bounding sphere.
// Per iteration: chunk skip iff (dist(c,center)-r)^2 >= U (+margins) -- then
// provably no d in the chunk changes (exact). U = upper bound on chunk's d,
// tightened to (dist+r)^2 when processed (lane-local, no reduce needed).
// All reduces compare (value desc, ORIGINAL index asc) -> sort permutation
// cannot change the winner; bit-exact vs reference.
__global__
__attribute__((amdgpu_flat_work_group_size(FPS_THR, FPS_THR)))
__attribute__((amdgpu_waves_per_eu(2, 2)))
void fps_transpose_kernel(const float* __restrict__ xyz,
                          const float* __restrict__ feat,
                          float* __restrict__ out,     // new_xyz at [0,12288)
                          int* __restrict__ cent,      // ws: 8*512 ints
                          int* __restrict__ map,       // ws: 8*16384 ints
                          float* __restrict__ ft,      // ws: (B,N,128) fp32
                          int use_ft)
{
    const int blk = blockIdx.x;
    const int tid = threadIdx.x;

    if (blk < NB) {
        const int b = blk;
        const float* xb = xyz + (size_t)b * NPTS * 3;
        int* gmap = map + b * NPTS;
        const int lane = tid & 63;
        const int wid  = tid >> 6;

        __shared__ int   s_hist[512];
        __shared__ float s_meta[8][32][4];
        __shared__ float s_v[2][32];
        __shared__ int   s_p[2][32];

        // ---- 1. histogram ----
        s_hist[tid] = 0;
        __syncthreads();
        for (int k = 0; k < PPT; ++k) {
            int p = k * FPS_THR + tid;
            int c = cell_of(xb[p * 3 + 0], xb[p * 3 + 1], xb[p * 3 + 2]);
            atomicAdd(&s_hist[c], 1);
        }
        __syncthreads();
        // ---- 2. inclusive scan (Hillis-Steele, in place) ----
        int mycount = s_hist[tid];
        for (int off = 1; off < 512; off <<= 1) {
            int v = (tid >= off) ? s_hist[tid - off] : 0;
            __syncthreads();
            s_hist[tid] += v;
            __syncthreads();
        }
        int excl = s_hist[tid] - mycount;
        __syncthreads();
        s_hist[tid] = excl;           // running scatter offsets
        __syncthreads();
        // ---- 3. scatter sorted->orig map to global ws ----
        for (int k = 0; k < PPT; ++k) {
            int p = k * FPS_THR + tid;
            int c = cell_of(xb[p * 3 + 0], xb[p * 3 + 1], xb[p * 3 + 2]);
            int pos = atomicAdd(&s_hist[c], 1);
            gmap[pos] = p;
        }
        __threadfence_block();
        __syncthreads();
        // ---- 4. gather sorted coords + orig idx into registers ----
        float px[PPT], py[PPT], pz[PPT], d[PPT];
        int   idx[PPT];
#pragma unroll
        for (int k = 0; k < PPT; ++k) {
            int pos = wid * 2048 + k * 64 + lane;
            int op  = gmap[pos];
            idx[k] = op;
            px[k] = xb[op * 3 + 0];
            py[k] = xb[op * 3 + 1];
            pz[k] = xb[op * 3 + 2];
            d[k]  = 1e10f;
        }
        // ---- 5. per-chunk bounding spheres (chunk k = 64 lanes' slot k) ----
#pragma unroll
        for (int k = 0; k < PPT; ++k) {
            float mnx = px[k], mxx = px[k];
            float mny = py[k], mxy = py[k];
            float mnz = pz[k], mxz = pz[k];
#pragma unroll
            for (int s = 1; s < 64; s <<= 1) {
                mnx = fminf(mnx, __shfl_xor(mnx, s, 64));
                mxx = fmaxf(mxx, __shfl_xor(mxx, s, 64));
                mny = fminf(mny, __shfl_xor(mny, s, 64));
                mxy = fmaxf(mxy, __shfl_xor(mxy, s, 64));
                mnz = fminf(mnz, __shfl_xor(mnz, s, 64));
                mxz = fmaxf(mxz, __shfl_xor(mxz, s, 64));
            }
            if (lane == 0) {
                float hx = (mxx - mnx) * 0.5f;
                float hy = (mxy - mny) * 0.5f;
                float hz = (mxz - mnz) * 0.5f;
                s_meta[wid][k][0] = (mnx + mxx) * 0.5f;
                s_meta[wid][k][1] = (mny + mxy) * 0.5f;
                s_meta[wid][k][2] = (mnz + mxz) * 0.5f;
                s_meta[wid][k][3] =
                    sqrtf(hx * hx + hy * hy + hz * hz) * 1.0001f + 1e-6f;
            }
        }
        __syncthreads();
        // lane l (and its mirror l+32) owns chunk l&31's bound state
        const float bmx = s_meta[wid][lane & 31][0];
        const float bmy = s_meta[wid][lane & 31][1];
        const float bmz = s_meta[wid][lane & 31][2];
        const float br  = s_meta[wid][lane & 31][3];
        float U = 1e10f;

        float cx = xb[0], cy = xb[1], cz = xb[2];
        if (tid == 0) {
            cent[b * NPOINT + 0] = 0;
            out[((size_t)b * NPOINT + 0) * 3 + 0] = cx;
            out[((size_t)b * NPOINT + 0) * 3 + 1] = cy;
            out[((size_t)b * NPOINT + 0) * 3 + 2] = cz;
        }

        // ---- 6. main loop ----
        for (int i = 1; i < NPOINT; ++i) {
            // chunk skip test (lane-parallel; lanes 32-63 mirror 0-31 so the
            // low 32 ballot bits are the chunk mask)
            float dcx = cx - bmx, dcy = cy - bmy, dcz = cz - bmz;
            float dc  = sqrtf(dcx * dcx + dcy * dcy + dcz * dcz);
            float t   = dc - br;
            bool skip = (t > 0.0f) && (t * t >= U + 2e-5f);
            unsigned mask = (unsigned)__ballot(skip);

            if (mask != 0xFFFFFFFFu) {
#pragma unroll
                for (int k = 0; k < PPT; ++k) {
                    if (!(mask & (1u << k))) {   // wave-uniform s_cbranch
                        float dx = __fsub_rn(px[k], cx);
                        float dy = __fsub_rn(py[k], cy);
                        float dz = __fsub_rn(pz[k], cz);
                        float dd = __fadd_rn(__fadd_rn(__fmul_rn(dx, dx),
                                                       __fmul_rn(dy, dy)),
                                             __fmul_rn(dz, dz));
                        d[k] = fminf(d[k], dd);   // np.minimum, exact
                    }
                }
            }
            // tighten U for processed chunks (valid: d_new <= (dc+r)^2)
            if (!((mask >> (lane & 31)) & 1u)) {
                float ub = dc + br;
                U = fminf(U, ub * ub * 1.0001f + 1e-6f);
            }
            // per-lane max over register-resident d (cheap, skip-independent)
            float vmax = d[0];
#pragma unroll
            for (int k = 1; k < PPT; ++k) vmax = fmaxf(vmax, d[k]);
            // recover the candidate's ORIGINAL index (descending k scan ->
            // smallest k with d[k]==vmax; fmax returns an operand so a match
            // exists)
            int bi = idx[PPT - 1];
#pragma unroll
            for (int k = PPT - 2; k >= 0; --k) bi = (d[k] == vmax) ? idx[k] : bi;

            float rv = vmax;
            int   rp = bi;
            // 16-lane row argmax (val desc, orig idx asc): 4 DPP steps
            DPP_ARG_STEP(rv, rp, 0xB1);
            DPP_ARG_STEP(rv, rp, 0x4E);
            DPP_ARG_STEP(rv, rp, 0x141);
            DPP_ARG_STEP(rv, rp, 0x140);
            const int par = i & 1;
            if ((lane & 15) == 0) {       // 4 row leaders per wave
                int slot = wid * 4 + (lane >> 4);
                s_v[par][slot] = rv;
                s_p[par][slot] = rp;
            }
            __syncthreads();              // the ONLY barrier per iteration
            float fv = s_v[par][lane & 31];
            int   fp = s_p[par][lane & 31];
            DPP_ARG_STEP(fv, fp, 0xB1);
            DPP_ARG_STEP(fv, fp, 0x4E);
            DPP_ARG_STEP(fv, fp, 0x141);
            DPP_ARG_STEP(fv, fp, 0x140);
            SHFL_ARG_STEP(fv, fp, 16);
            const int cur = __builtin_amdgcn_readfirstlane(fp);
            cx = xb[cur * 3 + 0];
            cy = xb[cur * 3 + 1];
            cz = xb[cur * 3 + 2];
            if (tid == 0) {
                cent[b * NPOINT + i] = cur;
                size_t o = ((size_t)b * NPOINT + i) * 3;
                out[o + 0] = cx; out[o + 1] = cy; out[o + 2] = cz;
            }
        }
    } else {
        if (!use_ft) return;
        // transpose feat (B,128,N) -> ft (B,N,128); 32x32 tile, 512 threads
        int t  = blk - NB;
        int b  = t >> 11;          // 2048 tiles per batch
        int r  = t & 2047;
        int ct = r >> 9;           // channel tile (4)
        int nt = r & 511;          // point tile (512)
        __shared__ float tile[32][33];
        int tx = tid & 31, ty = tid >> 5;   // ty 0..15
        tile[ty][tx] =
            feat[((size_t)b * NCH + ct * 32 + ty) * NPTS + nt * 32 + tx];
        tile[ty + 16][tx] =
            feat[((size_t)b * NCH + ct * 32 + ty + 16) * NPTS + nt * 32 + tx];
        __syncthreads();
        ft[((size_t)b * NPTS + nt * 32 + ty) * NCH + ct * 32 + tx] =
            tile[tx][ty];
        ft[((size_t)b * NPTS + nt * 32 + ty + 16) * NCH + ct * 32 + tx] =
            tile[tx][ty + 16];
    }
}

// -------- kernel 2: ball query + grouped max pool ---------------------------
__global__ __launch_bounds__(256, 4)
void query_pool_kernel(const float* __restrict__ xyz,
                       const float* __restrict__ feat,
                       const float* __restrict__ ft,
                       const int* __restrict__ cent,
                       float* __restrict__ out_sub,   // (B,128,512)
                       int use_ft)
{
    const int tid  = threadIdx.x;
    const int widx = tid >> 6;
    const int lane = tid & 63;
    const int w = blockIdx.x * 4 + widx;   // 0..4095
    const int b = w >> 9;
    const int s = w & 511;

    const float* xb = xyz + (size_t)b * NPTS * 3;
    const int ci = cent[b * NPOINT + s];
    const float sx = xb[ci * 3 + 0];
    const float sy = xb[ci * 3 + 1];
    const float sz = xb[ci * 3 + 2];
    const float snorm = __fadd_rn(__fadd_rn(__fmul_rn(sx, sx),
                                            __fmul_rn(sy, sy)),
                                  __fmul_rn(sz, sz));

    __shared__ int lidx[4][KNBR];
    int found = 0;
    for (int base = 0; base < NPTS && found < KNBR; base += 64) {
        int j = base + lane;
        float dx = xb[j * 3 + 0];
        float dy = xb[j * 3 + 1];
        float dz = xb[j * 3 + 2];
        float dn = __fadd_rn(__fadd_rn(__fmul_rn(dx, dx),
                                       __fmul_rn(dy, dy)),
                             __fmul_rn(dz, dz));
        float dot = __fadd_rn(__fadd_rn(__fmul_rn(sx, dx),
                                        __fmul_rn(sy, dy)),
                              __fmul_rn(sz, dz));
        // reference order: d = -2*dot; d += snorm; d += dnorm
        float d = __fadd_rn(__fadd_rn(__fmul_rn(-2.0f, dot), snorm), dn);
        bool inball = !(d > R2);
        unsigned long long mask = __ballot(inball);
        int before = (int)__popcll(mask & ((1ULL << lane) - 1ULL));
        int slot = found + before;
        if (inball && slot < KNBR) lidx[widx][slot] = j;
        found += (int)__popcll(mask);
    }
    int cnt = found < KNBR ? found : KNBR;   // cnt >= 1 (self in ball)
    __syncthreads();

    float a0 = -INFINITY, a1 = -INFINITY;
    if (use_ft) {
        for (int m = 0; m < cnt; ++m) {
            int i = lidx[widx][m];
            const float* row = ft + ((size_t)b * NPTS + i) * NCH;
            a0 = fmaxf(a0, row[lane]);
            a1 = fmaxf(a1, row[lane + 64]);
        }
    } else {
        for (int m = 0; m < cnt; ++m) {
            int i = lidx[widx][m];
            a0 = fmaxf(a0, feat[((size_t)b * NCH + lane) * NPTS + i]);
            a1 = fmaxf(a1, feat[((size_t)b * NCH + lane + 64) * NPTS + i]);
        }
    }
    out_sub[((size_t)b * NCH + lane) * NPOINT + s] = a0;
    out_sub[((size_t)b * NCH + lane + 64) * NPOINT + s] = a1;
}

extern "C" void kernel_launch(void* const* d_in, const int* in_sizes, int n_in,
                              void* d_out, int out_size, void* d_ws, size_t ws_size,
                              hipStream_t stream)
{
    const float* xyz  = (const float*)d_in[0];   // (8,16384,3)
    const float* feat = (const float*)d_in[1];   // (8,128,16384)
    float* out = (float*)d_out;                  // [new_xyz | sub_features]

    int*   cent = (int*)((char*)d_ws + CENT_OFF);
    int*   map  = (int*)((char*)d_ws + MAP_OFF);
    float* ft   = (float*)((char*)d_ws + FT_OFF);
    const size_t need_ft = (size_t)FT_OFF + (size_t)NB * NPTS * NCH * 4ull;
    int use_ft = (ws_size >= need_ft) ? 1 : 0;

    int nblocks1 = NB + (use_ft ? NB * (NCH / 32) * (NPTS / 32) : 0);
    hipLaunchKernelGGL(fps_transpose_kernel, dim3(nblocks1), dim3(FPS_THR), 0, stream,
                       xyz, feat, out, cent, map, ft, use_ft);

    hipLaunchKernelGGL(query_pool_kernel, dim3((NB * NPOINT) / 4), dim3(256), 0, stream,
                       xyz, feat, ft, cent, out + (size_t)NB * NPOINT * 3, use_ft);
}

// Round 7
// 1019.212 us; speedup vs baseline: 1.1337x; 1.0611x over previous
//
#include <hip/hip_runtime.h>
#include <stdint.h>
#include <math.h>

#define NB      8
#define NPTS    16384
#define NPOINT  512
#define NCH     128
#define KNBR    32
#define R2      0.04f

#define FPS_THR 512                  // 8 waves
#define PPT     32                   // chunks per wave (each chunk = 64 pts)

// ws layout
#define CENT_OFF 0                   // 8*512*4 = 16 KB
#define MAP_OFF  16384               // 8*16384*4 = 512 KB sorted->orig map
#define FT_OFF   (16384 + 524288)    // transposed features

// argmax step over (value desc, index asc) using DPP permute (VALU latency)
#define DPP_ARG_STEP(v, p, CTRL) do {                                          \
    float _ov = __builtin_bit_cast(float, __builtin_amdgcn_update_dpp(         \
        __builtin_bit_cast(int, (v)), __builtin_bit_cast(int, (v)),            \
        (CTRL), 0xF, 0xF, false));                                             \
    int _op = __builtin_amdgcn_update_dpp((p), (p), (CTRL), 0xF, 0xF, false);  \
    bool _t = (_ov > (v)) || ((_ov == (v)) && (_op < (p)));                    \
    (v) = _t ? _ov : (v);                                                      \
    (p) = _t ? _op : (p);                                                      \
} while (0)

// 8x8x8 morton cell id (9 bits) for a point in [0,1)^3
__device__ __forceinline__ int cell_of(float x, float y, float z) {
    int cx = (int)(x * 8.0f); cx = cx < 0 ? 0 : (cx > 7 ? 7 : cx);
    int cy = (int)(y * 8.0f); cy = cy < 0 ? 0 : (cy > 7 ? 7 : cy);
    int cz = (int)(z * 8.0f); cz = cz < 0 ? 0 : (cz > 7 ? 7 : cz);
    int m = 0;
    m |= ((cx & 1) << 2) | ((cx & 2) << 4) | ((cx & 4) << 6);
    m |= ((cy & 1) << 1) | ((cy & 2) << 3) | ((cy & 4) << 5);
    m |=  (cz & 1)       | ((cz & 2) << 2) | ((cz & 4) << 4);
    return m;
}

// -------- kernel 1: FPS with exact chunk skipping (blocks 0..7) + transpose -
// vs round 6: (a) chunks assigned to waves INTERLEAVED (wave w owns sorted
// chunks w, w+8, ...) so the active ball around each new centroid spreads
// across all 8 waves -> barrier wait ~= mean work, not max; (b) pre-barrier
// wave reduce is DPP-only (row_bcast15/31 replace the two ds_bpermute
// shuffles, ~240 cyc -> ~30 cyc), one partial per wave; (c) post-barrier
// reduce over 8 slots is 3 DPP steps (xor1, xor2, half-mirror = complete
// 8-element max network). Reduce comparator unchanged (value desc, ORIGINAL
// index asc) -> bit-exact vs reference regardless of reduction order.
__global__
__attribute__((amdgpu_flat_work_group_size(FPS_THR, FPS_THR)))
__attribute__((amdgpu_waves_per_eu(2, 2)))
void fps_transpose_kernel(const float* __restrict__ xyz,
                          const float* __restrict__ feat,
                          float* __restrict__ out,     // new_xyz at [0,12288)
                          int* __restrict__ cent,      // ws: 8*512 ints
                          int* __restrict__ map,       // ws: 8*16384 ints
                          float* __restrict__ ft,      // ws: (B,N,128) fp32
                          int use_ft)
{
    const int blk = blockIdx.x;
    const int tid = threadIdx.x;

    if (blk < NB) {
        const int b = blk;
        const float* xb = xyz + (size_t)b * NPTS * 3;
        int* gmap = map + b * NPTS;
        const int lane = tid & 63;
        const int wid  = tid >> 6;

        __shared__ int   s_hist[512];
        __shared__ float s_meta[8][PPT][4];
        __shared__ float s_v[2][8];
        __shared__ int   s_p[2][8];

        // ---- 1. histogram ----
        s_hist[tid] = 0;
        __syncthreads();
        for (int k = 0; k < PPT; ++k) {
            int p = k * FPS_THR + tid;
            int c = cell_of(xb[p * 3 + 0], xb[p * 3 + 1], xb[p * 3 + 2]);
            atomicAdd(&s_hist[c], 1);
        }
        __syncthreads();
        // ---- 2. inclusive scan (Hillis-Steele, in place) ----
        int mycount = s_hist[tid];
        for (int off = 1; off < 512; off <<= 1) {
            int v = (tid >= off) ? s_hist[tid - off] : 0;
            __syncthreads();
            s_hist[tid] += v;
            __syncthreads();
        }
        int excl = s_hist[tid] - mycount;
        __syncthreads();
        s_hist[tid] = excl;           // running scatter offsets
        __syncthreads();
        // ---- 3. scatter sorted->orig map to global ws ----
        for (int k = 0; k < PPT; ++k) {
            int p = k * FPS_THR + tid;
            int c = cell_of(xb[p * 3 + 0], xb[p * 3 + 1], xb[p * 3 + 2]);
            int pos = atomicAdd(&s_hist[c], 1);
            gmap[pos] = p;
        }
        __threadfence_block();
        __syncthreads();
        // ---- 4. gather sorted coords + orig idx into registers ----
        // INTERLEAVED: slot k of wave wid = global sorted chunk (k*8 + wid)
        float px[PPT], py[PPT], pz[PPT], d[PPT];
        int   idx[PPT];
#pragma unroll
        for (int k = 0; k < PPT; ++k) {
            int pos = (k * 8 + wid) * 64 + lane;
            int op  = gmap[pos];
            idx[k] = op;
            px[k] = xb[op * 3 + 0];
            py[k] = xb[op * 3 + 1];
            pz[k] = xb[op * 3 + 2];
            d[k]  = 1e10f;
        }
        // ---- 5. per-chunk bounding spheres (chunk k = this wave's slot k) --
#pragma unroll
        for (int k = 0; k < PPT; ++k) {
            float mnx = px[k], mxx = px[k];
            float mny = py[k], mxy = py[k];
            float mnz = pz[k], mxz = pz[k];
#pragma unroll
            for (int s = 1; s < 64; s <<= 1) {
                mnx = fminf(mnx, __shfl_xor(mnx, s, 64));
                mxx = fmaxf(mxx, __shfl_xor(mxx, s, 64));
                mny = fminf(mny, __shfl_xor(mny, s, 64));
                mxy = fmaxf(mxy, __shfl_xor(mxy, s, 64));
                mnz = fminf(mnz, __shfl_xor(mnz, s, 64));
                mxz = fmaxf(mxz, __shfl_xor(mxz, s, 64));
            }
            if (lane == 0) {
                float hx = (mxx - mnx) * 0.5f;
                float hy = (mxy - mny) * 0.5f;
                float hz = (mxz - mnz) * 0.5f;
                s_meta[wid][k][0] = (mnx + mxx) * 0.5f;
                s_meta[wid][k][1] = (mny + mxy) * 0.5f;
                s_meta[wid][k][2] = (mnz + mxz) * 0.5f;
                s_meta[wid][k][3] =
                    sqrtf(hx * hx + hy * hy + hz * hz) * 1.0001f + 1e-6f;
            }
        }
        __syncthreads();
        // lane l (and its mirror l+32) owns chunk-slot l&31's bound state
        const float bmx = s_meta[wid][lane & 31][0];
        const float bmy = s_meta[wid][lane & 31][1];
        const float bmz = s_meta[wid][lane & 31][2];
        const float br  = s_meta[wid][lane & 31][3];
        float U = 1e10f;

        float cx = xb[0], cy = xb[1], cz = xb[2];
        if (tid == 0) {
            cent[b * NPOINT + 0] = 0;
            out[((size_t)b * NPOINT + 0) * 3 + 0] = cx;
            out[((size_t)b * NPOINT + 0) * 3 + 1] = cy;
            out[((size_t)b * NPOINT + 0) * 3 + 2] = cz;
        }

        // ---- 6. main loop ----
        for (int i = 1; i < NPOINT; ++i) {
            // chunk skip test (lane-parallel; lanes 32-63 mirror 0-31)
            float dcx = cx - bmx, dcy = cy - bmy, dcz = cz - bmz;
            float dc  = sqrtf(dcx * dcx + dcy * dcy + dcz * dcz);
            float t   = dc - br;
            bool skip = (t > 0.0f) && (t * t >= U + 2e-5f);
            unsigned mask = (unsigned)__ballot(skip);

            if (mask != 0xFFFFFFFFu) {
#pragma unroll
                for (int k = 0; k < PPT; ++k) {
                    if (!(mask & (1u << k))) {   // wave-uniform s_cbranch
                        float dx = __fsub_rn(px[k], cx);
                        float dy = __fsub_rn(py[k], cy);
                        float dz = __fsub_rn(pz[k], cz);
                        float dd = __fadd_rn(__fadd_rn(__fmul_rn(dx, dx),
                                                       __fmul_rn(dy, dy)),
                                             __fmul_rn(dz, dz));
                        d[k] = fminf(d[k], dd);   // np.minimum, exact
                    }
                }
            }
            // tighten U for processed chunks (valid: d_new <= (dc+r)^2)
            if (!((mask >> (lane & 31)) & 1u)) {
                float ub = dc + br;
                U = fminf(U, ub * ub * 1.0001f + 1e-6f);
            }
            // per-lane max over register-resident d
            float vmax = d[0];
#pragma unroll
            for (int k = 1; k < PPT; ++k) vmax = fmaxf(vmax, d[k]);
            // recover the candidate's ORIGINAL index (descending k scan ->
            // smallest k with d[k]==vmax; fmax returns an operand so a match
            // exists)
            int bi = idx[PPT - 1];
#pragma unroll
            for (int k = PPT - 2; k >= 0; --k) bi = (d[k] == vmax) ? idx[k] : bi;

            float rv = vmax;
            int   rp = bi;
            // full-wave argmax, DPP-only (no ds_bpermute):
            // 4 steps reduce each 16-lane row; row_bcast15 then row_bcast31
            // accumulate row totals downward; lane 63 holds the wave total.
            DPP_ARG_STEP(rv, rp, 0xB1);    // xor 1
            DPP_ARG_STEP(rv, rp, 0x4E);    // xor 2
            DPP_ARG_STEP(rv, rp, 0x141);   // row_half_mirror
            DPP_ARG_STEP(rv, rp, 0x140);   // row_mirror
            DPP_ARG_STEP(rv, rp, 0x142);   // row_bcast15
            DPP_ARG_STEP(rv, rp, 0x143);   // row_bcast31
            const int par = i & 1;
            if (lane == 63) { s_v[par][wid] = rv; s_p[par][wid] = rp; }
            __syncthreads();              // the ONLY barrier per iteration
            // 8-slot reduce, 3 DPP steps (complete max network over 8):
            // xor1, xor2 -> max over aligned 4-group; half-mirror pairs the
            // two 4-groups -> every lane has the global winner.
            float fv = s_v[par][lane & 7];
            int   fp = s_p[par][lane & 7];
            DPP_ARG_STEP(fv, fp, 0xB1);
            DPP_ARG_STEP(fv, fp, 0x4E);
            DPP_ARG_STEP(fv, fp, 0x141);
            const int cur = __builtin_amdgcn_readfirstlane(fp);
            cx = xb[cur * 3 + 0];
            cy = xb[cur * 3 + 1];
            cz = xb[cur * 3 + 2];
            if (tid == 0) {
                cent[b * NPOINT + i] = cur;
                size_t o = ((size_t)b * NPOINT + i) * 3;
                out[o + 0] = cx; out[o + 1] = cy; out[o + 2] = cz;
            }
        }
    } else {
        if (!use_ft) return;
        // transpose feat (B,128,N) -> ft (B,N,128); 32x32 tile, 512 threads
        int t  = blk - NB;
        int b  = t >> 11;          // 2048 tiles per batch
        int r  = t & 2047;
        int ct = r >> 9;           // channel tile (4)
        int nt = r & 511;          // point tile (512)
        __shared__ float tile[32][33];
        int tx = tid & 31, ty = tid >> 5;   // ty 0..15
        tile[ty][tx] =
            feat[((size_t)b * NCH + ct * 32 + ty) * NPTS + nt * 32 + tx];
        tile[ty + 16][tx] =
            feat[((size_t)b * NCH + ct * 32 + ty + 16) * NPTS + nt * 32 + tx];
        __syncthreads();
        ft[((size_t)b * NPTS + nt * 32 + ty) * NCH + ct * 32 + tx] =
            tile[tx][ty];
        ft[((size_t)b * NPTS + nt * 32 + ty + 16) * NCH + ct * 32 + tx] =
            tile[tx][ty + 16];
    }
}

// -------- kernel 2: ball query + grouped max pool ---------------------------
__global__ __launch_bounds__(256, 4)
void query_pool_kernel(const float* __restrict__ xyz,
                       const float* __restrict__ feat,
                       const float* __restrict__ ft,
                       const int* __restrict__ cent,
                       float* __restrict__ out_sub,   // (B,128,512)
                       int use_ft)
{
    const int tid  = threadIdx.x;
    const int widx = tid >> 6;
    const int lane = tid & 63;
    const int w = blockIdx.x * 4 + widx;   // 0..4095
    const int b = w >> 9;
    const int s = w & 511;

    const float* xb = xyz + (size_t)b * NPTS * 3;
    const int ci = cent[b * NPOINT + s];
    const float sx = xb[ci * 3 + 0];
    const float sy = xb[ci * 3 + 1];
    const float sz = xb[ci * 3 + 2];
    const float snorm = __fadd_rn(__fadd_rn(__fmul_rn(sx, sx),
                                            __fmul_rn(sy, sy)),
                                  __fmul_rn(sz, sz));

    __shared__ int lidx[4][KNBR];
    int found = 0;
    for (int base = 0; base < NPTS && found < KNBR; base += 64) {
        int j = base + lane;
        float dx = xb[j * 3 + 0];
        float dy = xb[j * 3 + 1];
        float dz = xb[j * 3 + 2];
        float dn = __fadd_rn(__fadd_rn(__fmul_rn(dx, dx),
                                       __fmul_rn(dy, dy)),
                             __fmul_rn(dz, dz));
        float dot = __fadd_rn(__fadd_rn(__fmul_rn(sx, dx),
                                        __fmul_rn(sy, dy)),
                              __fmul_rn(sz, dz));
        // reference order: d = -2*dot; d += snorm; d += dnorm
        float d = __fadd_rn(__fadd_rn(__fmul_rn(-2.0f, dot), snorm), dn);
        bool inball = !(d > R2);
        unsigned long long mask = __ballot(inball);
        int before = (int)__popcll(mask & ((1ULL << lane) - 1ULL));
        int slot = found + before;
        if (inball && slot < KNBR) lidx[widx][slot] = j;
        found += (int)__popcll(mask);
    }
    int cnt = found < KNBR ? found : KNBR;   // cnt >= 1 (self in ball)
    __syncthreads();

    float a0 = -INFINITY, a1 = -INFINITY;
    if (use_ft) {
        for (int m = 0; m < cnt; ++m) {
            int i = lidx[widx][m];
            const float* row = ft + ((size_t)b * NPTS + i) * NCH;
            a0 = fmaxf(a0, row[lane]);
            a1 = fmaxf(a1, row[lane + 64]);
        }
    } else {
        for (int m = 0; m < cnt; ++m) {
            int i = lidx[widx][m];
            a0 = fmaxf(a0, feat[((size_t)b * NCH + lane) * NPTS + i]);
            a1 = fmaxf(a1, feat[((size_t)b * NCH + lane + 64) * NPTS + i]);
        }
    }
    out_sub[((size_t)b * NCH + lane) * NPOINT + s] = a0;
    out_sub[((size_t)b * NCH + lane + 64) * NPOINT + s] = a1;
}

extern "C" void kernel_launch(void* const* d_in, const int* in_sizes, int n_in,
                              void* d_out, int out_size, void* d_ws, size_t ws_size,
                              hipStream_t stream)
{
    const float* xyz  = (const float*)d_in[0];   // (8,16384,3)
    const float* feat = (const float*)d_in[1];   // (8,128,16384)
    float* out = (float*)d_out;                  // [new_xyz | sub_features]

    int*   cent = (int*)((char*)d_ws + CENT_OFF);
    int*   map  = (int*)((char*)d_ws + MAP_OFF);
    float* ft   = (float*)((char*)d_ws + FT_OFF);
    const size_t need_ft = (size_t)FT_OFF + (size_t)NB * NPTS * NCH * 4ull;
    int use_ft = (ws_size >= need_ft) ? 1 : 0;

    int nblocks1 = NB + (use_ft ? NB * (NCH / 32) * (NPTS / 32) : 0);
    hipLaunchKernelGGL(fps_transpose_kernel, dim3(nblocks1), dim3(FPS_THR), 0, stream,
                       xyz, feat, out, cent, map, ft, use_ft);

    hipLaunchKernelGGL(query_pool_kernel, dim3((NB * NPOINT) / 4), dim3(256), 0, stream,
                       xyz, feat, ft, cent, out + (size_t)NB * NPOINT * 3, use_ft);
}